// Round 9
// baseline (6030.531 us; speedup 1.0000x reference)
//
#include <hip/hip_runtime.h>
#include <cstdint>

// ---------------------------------------------------------------------------
// Threefry-2x32 (JAX partitionable-mode compatible), host + device.
// ---------------------------------------------------------------------------
__host__ __device__ inline uint32_t tf_rotl32(uint32_t x, uint32_t r) {
  return (x << r) | (x >> (32u - r));
}

__host__ __device__ inline void threefry2x32(uint32_t k0, uint32_t k1,
                                             uint32_t x0, uint32_t x1,
                                             uint32_t* o0, uint32_t* o1) {
  uint32_t ks0 = k0, ks1 = k1, ks2 = k0 ^ k1 ^ 0x1BD11BDAu;
  x0 += ks0; x1 += ks1;
#define TF_R(r) { x0 += x1; x1 = tf_rotl32(x1, r); x1 ^= x0; }
  TF_R(13) TF_R(15) TF_R(26) TF_R(6)
  x0 += ks1; x1 += ks2 + 1u;
  TF_R(17) TF_R(29) TF_R(16) TF_R(24)
  x0 += ks2; x1 += ks0 + 2u;
  TF_R(13) TF_R(15) TF_R(26) TF_R(6)
  x0 += ks0; x1 += ks1 + 3u;
  TF_R(17) TF_R(29) TF_R(16) TF_R(24)
  x0 += ks1; x1 += ks2 + 4u;
  TF_R(13) TF_R(15) TF_R(26) TF_R(6)
  x0 += ks2; x1 += ks0 + 5u;
#undef TF_R
  *o0 = x0; *o1 = x1;
}

// ---------------------------------------------------------------------------
// Problem dims
// ---------------------------------------------------------------------------
#define BSZ   8192
#define KIN   784
#define HID   800
#define NOUT  10
#define NSTEP 25

// Verified R8: golden = JAX-on-CPU (XLA -> Eigen gebp, AVX no-FMA build).
// Eigen k-panels for K=784: [0,264) [264,528) [528,784), committed C += P_i;
// per-element sequential ascending-k chain within each panel.
// Since a in {0,1,2}, rn(a*b) = a*b exactly, so fmaf == mul-then-add bitwise.
#define PANEL1 264
#define PANEL2 528

// ---------------------------------------------------------------------------
// Kernel 1: Poisson encoding (JAX-faithful: truncated 2^-23 grid).
// enc = temp + 1 in {0,1,2}; sp = 0.5*enc (exact power-of-2 relation).
// ---------------------------------------------------------------------------
__global__ __launch_bounds__(256) void enc_kernel(const float* __restrict__ inp,
                                                  uint8_t* __restrict__ enc,
                                                  uint32_t k0, uint32_t k1) {
  int j = blockIdx.x * blockDim.x + threadIdx.x;
  if (j >= BSZ * KIN) return;
  uint32_t o0, o1;
  threefry2x32(k0, k1, 0u, (uint32_t)j, &o0, &o1);
  uint32_t bits = o0 ^ o1;
  float r = __uint_as_float((bits >> 9) | 0x3f800000u) - 1.0f;
  float x = inp[j];
  bool cond = (2.0f * r <= fabsf(x));
  int s = (x > 0.0f) ? 1 : ((x < 0.0f) ? -1 : 0);
  enc[j] = (uint8_t)(1 + (cond ? s : 0));
}

// ---------------------------------------------------------------------------
// Kernel 2: g[b,j] = 0.5 * ((P0 + P1) + P2), Eigen panels at k=264,528.
// BK=8 divides 264/528/784, so commits are tile-aligned: 3-segment loop, no
// in-loop compares. Inner step fmaf (bit-exact: products are exact).
// Staging mapped so all LDS stores are <=2-way (free) bank accesses.
// BM=128 (batch), BN=32 (hidden). 256 threads, 4x4 acc per thread.
// ---------------------------------------------------------------------------
#define BM 128
#define BN 32
#define BK 8

__global__ __launch_bounds__(256) void gemm_kernel(const uint8_t* __restrict__ enc,
                                                   const float* __restrict__ w1,
                                                   float* __restrict__ g) {
  __shared__ float As[BK][BM];   // 4 KB
  __shared__ float Bs[BK][BN];   // 1 KB
  const int m0 = blockIdx.x * BM;
  const int n0 = blockIdx.y * BN;
  const int t  = threadIdx.x;
  const int tn = t % 8;          // 4 cols each -> 32
  const int tm = t / 8;          // 4 rows each -> 128
  // A staging: 128 rows x 8 k (u8). Thread: row t/2, 4 k's at (t&1)*4.
  // Store bank = arow%32 -> lanes pair per bank (2-way, free).
  const int arow  = t >> 1;
  const int akofs = (t & 1) * 4;
  // B staging: 32 rows x 8 k (f32). Thread: row t%32, k t/32 (one float).
  // Store bank = brow -> 32 distinct banks per half-wave (2-way, free).
  const int brow = t & 31;
  const int bk   = t >> 5;

  float acc[4][4] = {};   // current panel chain
  float tot[4][4] = {};   // committed C

  const int kends[3] = {PANEL1, PANEL2, KIN};
  int k0 = 0;
#pragma unroll
  for (int seg = 0; seg < 3; seg++) {
    const int kend = kends[seg];
    for (; k0 < kend; k0 += BK) {
      {
        const uint8_t* src = enc + (size_t)(m0 + arow) * KIN + k0 + akofs;
        uint32_t v = *(const uint32_t*)src;   // 4B aligned: 784%4==0, k0%8==0
#pragma unroll
        for (int i = 0; i < 4; i++)
          As[akofs + i][arow] = (float)((v >> (8 * i)) & 0xffu);
      }
      Bs[bk][brow] = w1[(size_t)(n0 + brow) * KIN + k0 + bk];
      __syncthreads();
#pragma unroll
      for (int kk = 0; kk < BK; kk++) {
        float a[4], b[4];
#pragma unroll
        for (int i = 0; i < 4; i++) a[i] = As[kk][tm * 4 + i];   // b128, broadcast
#pragma unroll
        for (int i = 0; i < 4; i++) b[i] = Bs[kk][tn * 4 + i];   // b128, broadcast
#pragma unroll
        for (int mi = 0; mi < 4; mi++)
#pragma unroll
          for (int ni = 0; ni < 4; ni++)
            acc[mi][ni] = fmaf(a[mi], b[ni], acc[mi][ni]);  // == mul+add bitwise
      }
      __syncthreads();
    }
    // Panel commit: C += P_i  (seg 0: 0 + P0 == P0 bitwise; -0 impossible here)
#pragma unroll
    for (int mi = 0; mi < 4; mi++)
#pragma unroll
      for (int ni = 0; ni < 4; ni++) {
        tot[mi][ni] = __fadd_rn(tot[mi][ni], acc[mi][ni]);
        acc[mi][ni] = 0.0f;
      }
  }
#pragma unroll
  for (int mi = 0; mi < 4; mi++) {
    float* dst = g + (size_t)(m0 + tm * 4 + mi) * HID + n0 + tn * 4;
#pragma unroll
    for (int ni = 0; ni < 4; ni++)
      dst[ni] = __fmul_rn(0.5f, tot[mi][ni]);   // exact 0.5 scale
  }
}

// ---------------------------------------------------------------------------
// Kernel 3: f32 membrane update + spike + mem2 accumulation.
// m = rn(rn(0.95f*mem) + rn(0.05f*g))  — mul/mul/add, no fma contraction;
// 0.05f == f32 of XLA's folded (1.0-0.95). Spike if m-1 > 0; reset m-1.
// ---------------------------------------------------------------------------
__global__ __launch_bounds__(256) void update_kernel(const float* __restrict__ g,
                                                     float* __restrict__ mem1,
                                                     const float* __restrict__ w2,
                                                     float* __restrict__ mem2) {
  __shared__ float w2s[NOUT * HID];   // 32 KB
  for (int i = threadIdx.x; i < NOUT * HID; i += 256) w2s[i] = w2[i];
  __syncthreads();

  const int wave = threadIdx.x / 64;
  const int lane = threadIdx.x % 64;
  const int b = blockIdx.x * 4 + wave;

  const float* grow = g + (size_t)b * HID;
  float* mrow = mem1 + (size_t)b * HID;

  float acc[NOUT];
#pragma unroll
  for (int i = 0; i < NOUT; i++) acc[i] = 0.0f;

  for (int j = lane; j < HID; j += 64) {
    float m = __fadd_rn(__fmul_rn(0.95f, mrow[j]), __fmul_rn(0.05f, grow[j]));
    bool spike = __fadd_rn(m, -1.0f) > 0.0f;
    mrow[j] = spike ? __fadd_rn(m, -1.0f) : m;
    if (spike) {
#pragma unroll
      for (int i = 0; i < NOUT; i++) acc[i] += w2s[i * HID + j];
    }
  }
  // mem2 never feeds back into spike decisions: reduction-order noise ~1e-7
  // << 3.6e-3 threshold.
#pragma unroll
  for (int i = 0; i < NOUT; i++) {
    float v = acc[i];
    for (int off = 32; off > 0; off >>= 1) v += __shfl_down(v, off);
    if (lane == 0) mem2[(size_t)b * NOUT + i] += v;
  }
}

// ---------------------------------------------------------------------------
// Kernel 4: out = mem2 / num_steps
// ---------------------------------------------------------------------------
__global__ __launch_bounds__(256) void finalize_kernel(const float* __restrict__ mem2,
                                                       const int* __restrict__ ns,
                                                       float* __restrict__ out) {
  int i = blockIdx.x * blockDim.x + threadIdx.x;
  if (i < BSZ * NOUT) out[i] = mem2[i] / (float)(*ns);
}

// ---------------------------------------------------------------------------
extern "C" void kernel_launch(void* const* d_in, const int* in_sizes, int n_in,
                              void* d_out, int out_size, void* d_ws, size_t ws_size,
                              hipStream_t stream) {
  const float* inp = (const float*)d_in[0];
  const float* w1  = (const float*)d_in[1];
  const float* w2  = (const float*)d_in[2];
  const int*   dns = (const int*)d_in[3];
  float* out = (float*)d_out;

  char* ws = (char*)d_ws;
  size_t off = 0;
  uint8_t* enc = (uint8_t*)(ws + off);  off += (size_t)BSZ * KIN;          // 6.4 MB
  off = (off + 255) & ~(size_t)255;
  float* g    = (float*)(ws + off);     off += (size_t)BSZ * HID * 4;      // 26.2 MB
  float* mem1 = (float*)(ws + off);     off += (size_t)BSZ * HID * 4;      // 26.2 MB
  float* mem2 = (float*)(ws + off);     off += (size_t)BSZ * NOUT * 4;     // 0.33 MB

  (void)hipMemsetAsync(mem1, 0, (size_t)BSZ * HID * 4, stream);
  (void)hipMemsetAsync(mem2, 0, (size_t)BSZ * NOUT * 4, stream);

  // Step keys: partitionable split — key_t = threefry((0,42), (0,t)).
  uint32_t keys[NSTEP][2];
  for (int t = 0; t < NSTEP; t++)
    threefry2x32(0u, 42u, 0u, (uint32_t)t, &keys[t][0], &keys[t][1]);

  const int n_elem = BSZ * KIN;
  for (int t = 0; t < NSTEP; t++) {
    enc_kernel<<<(n_elem + 255) / 256, 256, 0, stream>>>(inp, enc, keys[t][0], keys[t][1]);
    gemm_kernel<<<dim3(BSZ / BM, HID / BN), 256, 0, stream>>>(enc, w1, g);
    update_kernel<<<BSZ / 4, 256, 0, stream>>>(g, mem1, w2, mem2);
  }
  finalize_kernel<<<(BSZ * NOUT + 255) / 256, 256, 0, stream>>>(mem2, dns, out);
}

// Round 10
// 4919.573 us; speedup vs baseline: 1.2258x; 1.2258x over previous
//
#include <hip/hip_runtime.h>
#include <cstdint>

// ---------------------------------------------------------------------------
// Threefry-2x32 (JAX partitionable-mode compatible), host + device.
// ---------------------------------------------------------------------------
__host__ __device__ inline uint32_t tf_rotl32(uint32_t x, uint32_t r) {
  return (x << r) | (x >> (32u - r));
}

__host__ __device__ inline void threefry2x32(uint32_t k0, uint32_t k1,
                                             uint32_t x0, uint32_t x1,
                                             uint32_t* o0, uint32_t* o1) {
  uint32_t ks0 = k0, ks1 = k1, ks2 = k0 ^ k1 ^ 0x1BD11BDAu;
  x0 += ks0; x1 += ks1;
#define TF_R(r) { x0 += x1; x1 = tf_rotl32(x1, r); x1 ^= x0; }
  TF_R(13) TF_R(15) TF_R(26) TF_R(6)
  x0 += ks1; x1 += ks2 + 1u;
  TF_R(17) TF_R(29) TF_R(16) TF_R(24)
  x0 += ks2; x1 += ks0 + 2u;
  TF_R(13) TF_R(15) TF_R(26) TF_R(6)
  x0 += ks0; x1 += ks1 + 3u;
  TF_R(17) TF_R(29) TF_R(16) TF_R(24)
  x0 += ks1; x1 += ks2 + 4u;
  TF_R(13) TF_R(15) TF_R(26) TF_R(6)
  x0 += ks2; x1 += ks0 + 5u;
#undef TF_R
  *o0 = x0; *o1 = x1;
}

// ---------------------------------------------------------------------------
// Problem dims
// ---------------------------------------------------------------------------
#define BSZ   8192
#define KIN   784
#define HID   800
#define NOUT  10
#define NSTEP 25

// Verified R8: golden = JAX-on-CPU (XLA -> Eigen gebp). Eigen k-panels for
// K=784: [0,264) [264,528) [528,784), committed C += P_i; per-element
// sequential ascending-k chain within each panel. Since a in {0,1,2},
// rn(a*b) = a*b exactly, so fmaf == Eigen's mul-then-add bitwise.
// 528 = 33*16 (tile-aligned); 264 = 16*16 + 8 (split tile 16 at kk=8).

// ---------------------------------------------------------------------------
// Kernel 1: Poisson encoding (JAX-faithful: truncated 2^-23 grid).
// enc = temp + 1 in {0,1,2}; sp = 0.5*enc (exact power-of-2 relation).
// ---------------------------------------------------------------------------
__global__ __launch_bounds__(256) void enc_kernel(const float* __restrict__ inp,
                                                  uint8_t* __restrict__ enc,
                                                  uint32_t k0, uint32_t k1) {
  int j = blockIdx.x * blockDim.x + threadIdx.x;
  if (j >= BSZ * KIN) return;
  uint32_t o0, o1;
  threefry2x32(k0, k1, 0u, (uint32_t)j, &o0, &o1);
  uint32_t bits = o0 ^ o1;
  float r = __uint_as_float((bits >> 9) | 0x3f800000u) - 1.0f;
  float x = inp[j];
  bool cond = (2.0f * r <= fabsf(x));
  int s = (x > 0.0f) ? 1 : ((x < 0.0f) ? -1 : 0);
  enc[j] = (uint8_t)(1 + (cond ? s : 0));
}

// ---------------------------------------------------------------------------
// Kernel 2 (fused): g = 0.5*((P0+P1)+P2) Eigen-panel GEMM  +  membrane update
// + spike decision, all in-register. Writes mem1 (f32) and spk (u8), never g.
// BM=128, BN=32, BK=16, 256 threads, 4x4 acc/thread.
// B staged with XOR-quad swizzle: (k,n) at k*32 + ((n>>2)^((k>>1)&7))*4+(n&3)
//   -> stores <=2-way (free), reads b128 conflict-free broadcast.
// ---------------------------------------------------------------------------
#define BM 128
#define BN 32
#define BK 16

__global__ __launch_bounds__(256) void gemm_kernel(const uint8_t* __restrict__ enc,
                                                   const float* __restrict__ w1,
                                                   float* __restrict__ mem1,
                                                   uint8_t* __restrict__ spk) {
  __shared__ float As[BK * BM];   // 8 KB, layout k*BM + m
  __shared__ float Bs[BK * BN];   // 2 KB, swizzled
  const int m0 = blockIdx.x * BM;
  const int n0 = blockIdx.y * BN;
  const int t  = threadIdx.x;
  const int tn = t & 7;          // 4 cols each -> 32
  const int tm = t >> 3;         // 4 rows each -> 128
  // A staging: row t/2 (0..127), 8 k's at (t&1)*8. Store bank=arow%32: 2-way.
  const int arow  = t >> 1;
  const int akofs = (t & 1) * 8;
  // B staging: row t/8 (0..31), float2 at k=(t&7)*2. Global: 8 lanes = 64 B
  // contiguous per row. Swizzled store: q = t&7 -> <=2-way banks.
  const int brow  = t >> 3;
  const int bkofs = (t & 7) * 2;
  const int bswz  = (((brow >> 2) ^ (t & 7)) << 2) + (brow & 3);

  float acc[4][4] = {};   // current panel chain
  float tot[4][4] = {};   // committed C

#define COMMIT()                                                   \
  {                                                                \
    _Pragma("unroll") for (int mi = 0; mi < 4; mi++)               \
      _Pragma("unroll") for (int ni = 0; ni < 4; ni++) {           \
        tot[mi][ni] = __fadd_rn(tot[mi][ni], acc[mi][ni]);         \
        acc[mi][ni] = 0.0f;                                        \
      }                                                            \
  }

#define MAC_RANGE(KB, KE)                                          \
  {                                                                \
    _Pragma("unroll") for (int kk = (KB); kk < (KE); kk++) {       \
      const int q = (kk >> 1) & 7;                                 \
      float a[4], b[4];                                            \
      *(float4*)a = *(const float4*)&As[kk * BM + (tm << 2)];      \
      *(float4*)b = *(const float4*)&Bs[kk * BN + (((tn ^ q)) << 2)]; \
      _Pragma("unroll") for (int mi = 0; mi < 4; mi++)             \
        _Pragma("unroll") for (int ni = 0; ni < 4; ni++)           \
          acc[mi][ni] = fmaf(a[mi], b[ni], acc[mi][ni]);           \
    }                                                              \
  }

  int k0 = 0;
  for (int tile = 0; tile < 49; tile++, k0 += BK) {
    // A tile: 128 x 16 u8 -> f32
    {
      const uint8_t* src = enc + (size_t)(m0 + arow) * KIN + k0 + akofs;
      uint2 v = *(const uint2*)src;   // 8B aligned: 784%8==0, k0%16==0
      As[(akofs + 0) * BM + arow] = (float)( v.x        & 0xffu);
      As[(akofs + 1) * BM + arow] = (float)((v.x >>  8) & 0xffu);
      As[(akofs + 2) * BM + arow] = (float)((v.x >> 16) & 0xffu);
      As[(akofs + 3) * BM + arow] = (float)((v.x >> 24)        );
      As[(akofs + 4) * BM + arow] = (float)( v.y        & 0xffu);
      As[(akofs + 5) * BM + arow] = (float)((v.y >>  8) & 0xffu);
      As[(akofs + 6) * BM + arow] = (float)((v.y >> 16) & 0xffu);
      As[(akofs + 7) * BM + arow] = (float)((v.y >> 24)        );
    }
    // B tile: 32 x 16 f32, swizzled store
    {
      const float* src = w1 + (size_t)(n0 + brow) * KIN + k0 + bkofs;
      float2 v = *(const float2*)src;
      Bs[(bkofs + 0) * BN + bswz] = v.x;
      Bs[(bkofs + 1) * BN + bswz] = v.y;   // same q as bkofs (even k)
    }
    __syncthreads();
    if (tile == 16) {            // k=256..272 contains panel boundary 264
      MAC_RANGE(0, 8)
      COMMIT()                   // tot = P0  (0 + P0 exact)
      MAC_RANGE(8, 16)
    } else {
      MAC_RANGE(0, 16)
    }
    __syncthreads();
    if (tile == 32) COMMIT()     // k=528 boundary: tot = P0 + P1
  }
  COMMIT()                       // tot = (P0+P1) + P2

  // ---- fused epilogue: g = 0.5*tot; membrane update; spike ----
#pragma unroll
  for (int mi = 0; mi < 4; mi++) {
    const size_t row = (size_t)(m0 + (tm << 2) + mi);
    float* mp = mem1 + row * HID + n0 + (tn << 2);
    float mold[4];
    *(float4*)mold = *(const float4*)mp;
    float mnew[4];
    uint32_t sbits = 0;
#pragma unroll
    for (int ni = 0; ni < 4; ni++) {
      float gv  = __fmul_rn(0.5f, tot[mi][ni]);                       // exact
      float m   = __fadd_rn(__fmul_rn(0.95f, mold[ni]), __fmul_rn(0.05f, gv));
      float thr = __fadd_rn(m, -1.0f);
      bool spike = thr > 0.0f;
      mnew[ni] = spike ? thr : m;        // reset m-1 == thr bitwise
      sbits |= (spike ? 1u : 0u) << (8 * ni);
    }
    *(float4*)mp = *(const float4*)mnew;
    *(uint32_t*)(spk + row * HID + n0 + (tn << 2)) = sbits;
  }
#undef MAC_RANGE
#undef COMMIT
}

// ---------------------------------------------------------------------------
// Kernel 3: spike x w2^T accumulation into mem2. One wave per batch row.
// mem2 never feeds back into spike decisions: order noise ~1e-7 << threshold.
// ---------------------------------------------------------------------------
__global__ __launch_bounds__(256) void spike_out_kernel(const uint8_t* __restrict__ spk,
                                                        const float* __restrict__ w2,
                                                        float* __restrict__ mem2) {
  __shared__ float w2s[NOUT * HID];   // 32 KB
  for (int i = threadIdx.x; i < NOUT * HID; i += 256) w2s[i] = w2[i];
  __syncthreads();

  const int wave = threadIdx.x / 64;
  const int lane = threadIdx.x % 64;
  const int b = blockIdx.x * 4 + wave;
  const uint8_t* srow = spk + (size_t)b * HID;

  float acc[NOUT];
#pragma unroll
  for (int i = 0; i < NOUT; i++) acc[i] = 0.0f;

  for (int j = lane; j < HID; j += 64) {
    if (srow[j]) {
#pragma unroll
      for (int i = 0; i < NOUT; i++) acc[i] += w2s[i * HID + j];
    }
  }
#pragma unroll
  for (int i = 0; i < NOUT; i++) {
    float v = acc[i];
    for (int off = 32; off > 0; off >>= 1) v += __shfl_down(v, off);
    if (lane == 0) mem2[(size_t)b * NOUT + i] += v;
  }
}

// ---------------------------------------------------------------------------
// Kernel 4: out = mem2 / num_steps
// ---------------------------------------------------------------------------
__global__ __launch_bounds__(256) void finalize_kernel(const float* __restrict__ mem2,
                                                       const int* __restrict__ ns,
                                                       float* __restrict__ out) {
  int i = blockIdx.x * blockDim.x + threadIdx.x;
  if (i < BSZ * NOUT) out[i] = mem2[i] / (float)(*ns);
}

// ---------------------------------------------------------------------------
extern "C" void kernel_launch(void* const* d_in, const int* in_sizes, int n_in,
                              void* d_out, int out_size, void* d_ws, size_t ws_size,
                              hipStream_t stream) {
  const float* inp = (const float*)d_in[0];
  const float* w1  = (const float*)d_in[1];
  const float* w2  = (const float*)d_in[2];
  const int*   dns = (const int*)d_in[3];
  float* out = (float*)d_out;

  char* ws = (char*)d_ws;
  size_t off = 0;
  uint8_t* enc = (uint8_t*)(ws + off);  off += (size_t)BSZ * KIN;          // 6.4 MB
  off = (off + 255) & ~(size_t)255;
  uint8_t* spk = (uint8_t*)(ws + off);  off += (size_t)BSZ * HID;          // 6.6 MB
  off = (off + 255) & ~(size_t)255;
  float* mem1 = (float*)(ws + off);     off += (size_t)BSZ * HID * 4;      // 26.2 MB
  float* mem2 = (float*)(ws + off);     off += (size_t)BSZ * NOUT * 4;     // 0.33 MB

  (void)hipMemsetAsync(mem1, 0, (size_t)BSZ * HID * 4, stream);
  (void)hipMemsetAsync(mem2, 0, (size_t)BSZ * NOUT * 4, stream);

  // Step keys: partitionable split — key_t = threefry((0,42), (0,t)).
  uint32_t keys[NSTEP][2];
  for (int t = 0; t < NSTEP; t++)
    threefry2x32(0u, 42u, 0u, (uint32_t)t, &keys[t][0], &keys[t][1]);

  const int n_elem = BSZ * KIN;
  for (int t = 0; t < NSTEP; t++) {
    enc_kernel<<<(n_elem + 255) / 256, 256, 0, stream>>>(inp, enc, keys[t][0], keys[t][1]);
    gemm_kernel<<<dim3(BSZ / BM, HID / BN), 256, 0, stream>>>(enc, w1, mem1, spk);
    spike_out_kernel<<<BSZ / 4, 256, 0, stream>>>(spk, w2, mem2);
  }
  finalize_kernel<<<(BSZ * NOUT + 255) / 256, 256, 0, stream>>>(mem2, dns, out);
}